// Round 1
// baseline (1241.115 us; speedup 1.0000x reference)
//
#include <hip/hip_runtime.h>
#include <math.h>

// Problem constants
#define B_SZ   64
#define Q_SZ   1024
#define H_SZ   64
#define W_SZ   64
#define RWIN   16
#define CWIN   16
#define CTX_SZ 1024
#define ROWS   65   // H+1 (NaN-padded)
#define COLS   65

// ws layout (float offsets)
//  v      : [0      , 65536)   (B*Q)
//  a_t    : [65536  , 81920)   (B*256)
//  w_attn : [81920  , 98304)   (B*256)
//  ridx   : [98304  , 99328)   (B*16 ints)
//  cidx   : [99328  , 100352)  (B*16 ints)
//  rexp   : [100352 , 101376)  (B*16)
//  cexp   : [101376 , 102400)  (B*16)

__global__ void k_zero(float* ws) {
    int idx = blockIdx.x * 256 + threadIdx.x;   // grid 320*256 = 81920 = v + a_t
    ws[idx] = 0.f;
}

// Per-batch predictive alignment: p = sigmoid(c_t @ w_p^T) * 63, window indices + gaussian shift
__global__ void k_params(const float* __restrict__ c_t, const float* __restrict__ w_p,
                         int* __restrict__ ridx, int* __restrict__ cidx,
                         float* __restrict__ rexp, float* __restrict__ cexp) {
    int b = blockIdx.x, l = threadIdx.x;  // 64 threads
    float d0 = 0.f, d1 = 0.f;
    for (int c = l; c < CTX_SZ; c += 64) {
        float x = c_t[b * CTX_SZ + c];
        d0 += x * w_p[c];
        d1 += x * w_p[CTX_SZ + c];
    }
    for (int off = 32; off; off >>= 1) {
        d0 += __shfl_xor(d0, off, 64);
        d1 += __shfl_xor(d1, off, 64);
    }
    float px = 63.f / (1.f + expf(-d0));   // loc0 * (rows-2)
    float py = 63.f / (1.f + expf(-d1));
    if (l < 16) {
        int vi = (int)rintf(px) + (l - 7);             // offs -7..8
        vi = vi < 0 ? 0 : (vi > 65 ? 65 : vi);         // clip [0,65]
        if (vi == 65) vi = 0;                          // mod 65
        ridx[b * 16 + l] = vi;
        float d = ((float)(vi - 1 > 0 ? vi - 1 : 0) - px) * 0.125f;
        rexp[b * 16 + l] = 2.f * d * d;
    } else if (l < 32) {
        int k = l - 16;
        int vi = (int)rintf(py) + (k - 7);
        vi = vi < 0 ? 0 : (vi > 65 ? 65 : vi);
        if (vi == 65) vi = 0;
        cidx[b * 16 + k] = vi;
        float d = ((float)(vi - 1 > 0 ? vi - 1 : 0) - py) * 0.125f;
        cexp[b * 16 + k] = 2.f * d * d;
    }
}

// v = c_t @ w_a  (B x Q), split over c-chunks, atomically accumulated
__global__ void k_gemv(const float* __restrict__ c_t, const float* __restrict__ w_a,
                       float* __restrict__ v) {
    int cc = blockIdx.x;   // 8 chunks of 128 ctx
    int bt = blockIdx.y;   // 16 tiles of 4 batches
    int t  = threadIdx.x;  // 256
    float acc[4][4] = {};
    const float* wa = w_a + (size_t)cc * 128 * Q_SZ + t;
    const float* ct = c_t + (size_t)bt * 4 * CTX_SZ + cc * 128;
    for (int c = 0; c < 128; ++c) {
        float w0 = wa[c * Q_SZ];
        float w1 = wa[c * Q_SZ + 256];
        float w2 = wa[c * Q_SZ + 512];
        float w3 = wa[c * Q_SZ + 768];
#pragma unroll
        for (int bb = 0; bb < 4; ++bb) {
            float s = ct[bb * CTX_SZ + c];
            acc[bb][0] = fmaf(s, w0, acc[bb][0]);
            acc[bb][1] = fmaf(s, w1, acc[bb][1]);
            acc[bb][2] = fmaf(s, w2, acc[bb][2]);
            acc[bb][3] = fmaf(s, w3, acc[bb][3]);
        }
    }
#pragma unroll
    for (int bb = 0; bb < 4; ++bb)
#pragma unroll
        for (int k = 0; k < 4; ++k)
            atomicAdd(&v[(bt * 4 + bb) * Q_SZ + k * 256 + t], acc[bb][k]);
}

// Pass A: a_t[b, i*16+j] = sum_q win[b,(i,j),q] * v[b,q]
// thread <-> window position (i,j); loop over a 64-q chunk; coalesced 64B row segments
__global__ void k_score(const float* __restrict__ qin, const float* __restrict__ v,
                        const int* __restrict__ ridx, const int* __restrict__ cidx,
                        float* __restrict__ a_t) {
    int b = blockIdx.x, qc = blockIdx.y;   // qc: 16 chunks of 64 q
    int t = threadIdx.x, i = t >> 4, j = t & 15;
    int row = ridx[b * 16 + i], col = cidx[b * 16 + j];
    float acc = 0.f;
    if (row > 0 && col > 0) {
        const float* base = qin + ((size_t)(b * Q_SZ + qc * 64) << 12) + (row - 1) * W_SZ + (col - 1);
        const float* vv   = v + b * Q_SZ + qc * 64;
#pragma unroll 8
        for (int q = 0; q < 64; ++q)
            acc = fmaf(base[(size_t)q << 12], vv[q], acc);
    }
    atomicAdd(&a_t[b * 256 + t], acc);
}

// Softmax over the 256 window positions (masked), per batch
__global__ void k_softmax(const float* __restrict__ a_t,
                          const int* __restrict__ ridx, const int* __restrict__ cidx,
                          const float* __restrict__ rexp, const float* __restrict__ cexp,
                          float* __restrict__ w_attn) {
    int b = blockIdx.x, t = threadIdx.x;  // 256 threads
    int i = t >> 4, j = t & 15;
    int row = ridx[b * 16 + i], col = cidx[b * 16 + j];
    bool valid = (row > 0) && (col > 0);
    float s = valid ? (a_t[b * 256 + t] - (rexp[b * 16 + i] + cexp[b * 16 + j]))
                    : -INFINITY;
    __shared__ float red[4];
    float m = s;
    for (int off = 32; off; off >>= 1) m = fmaxf(m, __shfl_xor(m, off, 64));
    if ((t & 63) == 0) red[t >> 6] = m;
    __syncthreads();
    m = fmaxf(fmaxf(red[0], red[1]), fmaxf(red[2], red[3]));
    float e = valid ? expf(s - m) : 0.f;
    float sum = e;
    for (int off = 32; off; off >>= 1) sum += __shfl_xor(sum, off, 64);
    __syncthreads();
    if ((t & 63) == 0) red[t >> 6] = sum;
    __syncthreads();
    sum = red[0] + red[1] + red[2] + red[3];
    w_attn[b * 256 + t] = e / sum;
}

// Pass B: s_t[b,q] = sum_w w_attn[b,w] * win[b,w,q]
// lane mapping (4 q x 16 cols) keeps reads row-contiguous; 16-lane shuffle reduce per q
__global__ void k_out(const float* __restrict__ qin, const float* __restrict__ w_attn,
                      const int* __restrict__ ridx, const int* __restrict__ cidx,
                      float* __restrict__ out) {
    int b = blockIdx.x, qc = blockIdx.y;   // qc: 16 chunks of 64 q
    int t = threadIdx.x;
    int wv = t >> 6, l = t & 63, ql = l >> 4, j = l & 15;
    int col = cidx[b * 16 + j];
    bool cval = col > 0;
    float wreg[16];
    int   rows[16];
#pragma unroll
    for (int i = 0; i < 16; ++i) {
        wreg[i] = w_attn[b * 256 + i * 16 + j];
        rows[i] = ridx[b * 16 + i];
    }
#pragma unroll
    for (int rep = 0; rep < 4; ++rep) {
        int q = qc * 64 + wv * 16 + rep * 4 + ql;
        const float* base = qin + ((size_t)(b * Q_SZ + q) << 12) + (col - 1);
        float acc = 0.f;
#pragma unroll
        for (int i = 0; i < 16; ++i) {
            if (cval && rows[i] > 0)
                acc += base[(rows[i] - 1) * W_SZ] * wreg[i];
        }
        for (int off = 1; off < 16; off <<= 1) acc += __shfl_xor(acc, off, 64);
        if (j == 0) out[b * Q_SZ + q] = acc;
    }
}

extern "C" void kernel_launch(void* const* d_in, const int* in_sizes, int n_in,
                              void* d_out, int out_size, void* d_ws, size_t ws_size,
                              hipStream_t stream) {
    const float* q_i = (const float*)d_in[0];
    const float* c_t = (const float*)d_in[1];
    const float* w_a = (const float*)d_in[2];
    const float* w_p = (const float*)d_in[3];
    float* out = (float*)d_out;

    float* ws     = (float*)d_ws;
    float* v      = ws;
    float* a_t    = ws + 65536;
    float* w_attn = ws + 81920;
    int*   ridx   = (int*)(ws + 98304);
    int*   cidx   = (int*)(ws + 99328);
    float* rexp   = ws + 100352;
    float* cexp   = ws + 101376;

    k_zero   <<<dim3(320),      dim3(256), 0, stream>>>(ws);
    k_params <<<dim3(B_SZ),     dim3(64),  0, stream>>>(c_t, w_p, ridx, cidx, rexp, cexp);
    k_gemv   <<<dim3(8, 16),    dim3(256), 0, stream>>>(c_t, w_a, v);
    k_score  <<<dim3(B_SZ, 16), dim3(256), 0, stream>>>(q_i, v, ridx, cidx, a_t);
    k_softmax<<<dim3(B_SZ),     dim3(256), 0, stream>>>(a_t, ridx, cidx, rexp, cexp, w_attn);
    k_out    <<<dim3(B_SZ, 16), dim3(256), 0, stream>>>(q_i, w_attn, ridx, cidx, out);
}